// Round 6
// baseline (1070.281 us; speedup 1.0000x reference)
//
#include <hip/hip_runtime.h>
#include <cstdint>

#define NB   4      // batches
#define NPT  8192   // points
#define NC   256    // feature channels
#define NS   1024   // FPS samples
#define NK   64     // neighbors per ball
#define FPT  16     // points per thread in FPS (8192 / 512 threads)

typedef float v2f __attribute__((ext_vector_type(2)));

// ---------------------------------------------------------------------------
// DPP max step (f32, old=0 fill — safe: all reduced values >= 0).
// ---------------------------------------------------------------------------
template <int CTRL, int RMASK>
__device__ __forceinline__ float dpp_max_step(float x) {
    const int t = __builtin_amdgcn_update_dpp(
        0, __float_as_int(x), CTRL, RMASK, 0xf, false);
    return fmaxf(x, __int_as_float(t));
}
__device__ __forceinline__ float wave_max_f32(float x) {
    x = dpp_max_step<0x111, 0xf>(x);  // row_shr:1
    x = dpp_max_step<0x112, 0xf>(x);  // row_shr:2
    x = dpp_max_step<0x114, 0xf>(x);  // row_shr:4
    x = dpp_max_step<0x118, 0xf>(x);  // row_shr:8
    x = dpp_max_step<0x142, 0xa>(x);  // row_bcast:15 -> rows 1,3
    x = dpp_max_step<0x143, 0xc>(x);  // row_bcast:31 -> rows 2,3
    return x;                          // lane 63 holds wave max
}

// ---------------------------------------------------------------------------
// Kernel 1: farthest point sampling. One 512-thread block (8 waves) per batch.
// Cross-wave winner exchange, latency-minimized (no atomics, 2 LDS hops):
//  - each wave's delegate lane writes (bestval, bestidx) to its OWN slot in
//    cval/cidx[wb][8] (double-buffered by step parity; one writer per slot;
//    slot read at step s+1 happens after barrier(s) -> race-free).
//  - loop top: lanes read slot (lane&7), 3-step DPP max over the 8 values,
//    smax = readlane(.,7); ballot(v==smax) -> lowest lane l0 = lowest wave
//    with the max value. Waves own ascending contiguous index blocks, so
//    lowest-wave-among-ties == smallest point index — identical winner to the
//    previous u64 (valbits<<32 | ~idx) max key. widx = readlane(cidx, l0).
//  - centroid xyz: single uniform ds_read_b128 from Pts[widx].
// First-occurrence argmax within a wave: VERIFIED machinery unchanged
// (x-half/y-half split, strict->, ballot+ffs lowest lane).
// NOTE: non-FMA left-to-right distance arithmetic (contract off) is VERIFIED
// bit-exact vs the reference (rounds 1-5). Do not "optimize" into FMA.
// ---------------------------------------------------------------------------
__global__ __launch_bounds__(512) void fps_kernel(
    const float* __restrict__ xyz, float* __restrict__ sample_xyz)
{
    const int b    = blockIdx.x;
    const int tid  = threadIdx.x;
    const int lane = tid & 63;
    const int wv   = tid >> 6;

    __shared__ float4 Pts[NPT];          // 128 KB: xyz (+pad) per point
    __shared__ float  Samp[NS * 3];      // 12 KB result buffer
    __shared__ float  cval[2][8];        // per-wave candidate value
    __shared__ int    cidx[2][8];        // per-wave candidate index

    const float* base = xyz + (size_t)b * NPT * 3;

    v2f px[8], py[8], pz[8], md[8];
#pragma unroll
    for (int j = 0; j < 8; ++j) {
        const int pa = tid * FPT + j;        // x-half point
        const int pb = tid * FPT + 8 + j;    // y-half point
        const float ax = base[pa * 3 + 0], ay = base[pa * 3 + 1], az = base[pa * 3 + 2];
        const float bx = base[pb * 3 + 0], by = base[pb * 3 + 1], bz = base[pb * 3 + 2];
        px[j] = (v2f){ax, bx};
        py[j] = (v2f){ay, by};
        pz[j] = (v2f){az, bz};
        md[j] = (v2f){__builtin_inff(), __builtin_inff()};
        Pts[pa] = (float4){ax, ay, az, 0.0f};
        Pts[pb] = (float4){bx, by, bz, 0.0f};
    }
    if (tid < 8) {
        // step 0 must select point 0: give slot 0 the dominant value
        cval[0][tid] = (tid == 0) ? 3.0e38f : -1.0f;
        cidx[0][tid] = 0;
    }
    __syncthreads();

    for (int s = 0; s < NS; ++s) {
        const int rb = s & 1;        // read buffer
        const int wb = rb ^ 1;       // write buffer

        // ---- phase A: pick global winner from the 8 wave candidates ----
        const int   g  = lane & 7;
        const float v  = cval[rb][g];
        const int   ci = cidx[rb][g];
        float r = v;
        r = dpp_max_step<0x111, 0xf>(r);   // row_shr:1
        r = dpp_max_step<0x112, 0xf>(r);   // row_shr:2
        r = dpp_max_step<0x114, 0xf>(r);   // row_shr:4  -> lane7 = max(v0..v7)
        const float smax = __int_as_float(
            __builtin_amdgcn_readlane(__float_as_int(r), 7));
        const unsigned long long mA = __ballot(v == smax);
        const int l0   = __ffsll((long long)mA) - 1;   // lowest wave with max
        const int widx = __builtin_amdgcn_readlane(ci, l0);

        const float4 cen = Pts[widx];      // uniform ds_read_b128 broadcast
        const float sx = cen.x, sy = cen.y, sz = cen.z;
        if (tid == 0) {
            Samp[s * 3 + 0] = sx; Samp[s * 3 + 1] = sy; Samp[s * 3 + 2] = sz;
        }

        // ---- phase B: min_d update + per-thread first-occurrence max ----
        const v2f sxv = (v2f){sx, sx};
        const v2f syv = (v2f){sy, sy};
        const v2f szv = (v2f){sz, sz};

        v2f best2 = (v2f){-1.0f, -1.0f};
        int jx = 0, jy = 0;
        {
#pragma clang fp contract(off)
#pragma unroll
            for (int j = 0; j < 8; ++j) {
                // EXACT reference arithmetic per element:
                // ((dx*dx + dy*dy) + dz*dz), no FMA (contract off)
                const v2f dx = px[j] - sxv;
                const v2f dy = py[j] - syv;
                const v2f dz = pz[j] - szv;
                const v2f d  = (dx * dx + dy * dy) + dz * dz;
                const v2f m  = __builtin_elementwise_min(md[j], d);
                md[j] = m;
                // strict > keeps first occurrence within each half
                if (m.x > best2.x) jx = j;
                if (m.y > best2.y) jy = j;
                best2 = __builtin_elementwise_max(best2, m);
            }
        }
        // combine halves: every x-half index < every y-half index
        float    bestval;
        unsigned bestidx;
        if (best2.y > best2.x) { bestval = best2.y; bestidx = (unsigned)(tid * FPT + 8 + jy); }
        else                   { bestval = best2.x; bestidx = (unsigned)(tid * FPT + jx); }

        // ---- phase C: wave max via DPP, first achieving lane via ballot ----
        const float wmax = wave_max_f32(bestval);
        const float smaxw = __int_as_float(
            __builtin_amdgcn_readlane(__float_as_int(wmax), 63));
        const unsigned long long mC = __ballot(bestval == smaxw);
        const int wl = __ffsll((long long)mC) - 1;     // lowest lane

        // ---- phase D: delegate lane publishes this wave's candidate ----
        if (lane == wl) {
            cval[wb][wv] = bestval;          // == smaxw
            cidx[wb][wv] = (int)bestidx;
        }
        __syncthreads();
    }

    // coalesced flush of the sample buffer
    float* o = sample_xyz + (size_t)b * NS * 3;
    for (int i = tid; i < NS * 3; i += 512) o[i] = Samp[i];
}

// ---------------------------------------------------------------------------
// Kernel 2: ball query (first-64 in-radius indices, ascending) + feature
// gather. One 256-thread block per (b, s) centroid. Early-exit scan.
// d2 = na + nb - 2*dot; dot is an FMA CHAIN (XLA dot_general semantics),
// na/nb are non-FMA square-sums (XLA reduce semantics). VERIFIED rounds 2-5.
// ---------------------------------------------------------------------------
__global__ __launch_bounds__(256) void bq_gather_kernel(
    const float* __restrict__ xyz, const float* __restrict__ feat,
    const float* __restrict__ sample_xyz, float* __restrict__ out_feat)
{
    const int s   = blockIdx.x;
    const int b   = blockIdx.y;
    const int tid = threadIdx.x;

    __shared__ int   list[NK];
    __shared__ int   wavecnt[4];
    __shared__ float cen[3];

    if (tid < 3) cen[tid] = sample_xyz[((size_t)b * NS + s) * 3 + tid];
    __syncthreads();
    const float sx = cen[0], sy = cen[1], sz = cen[2];
    const float na = __fadd_rn(
        __fadd_rn(__fmul_rn(sx, sx), __fmul_rn(sy, sy)), __fmul_rn(sz, sz));
    const float* bxyz = xyz + (size_t)b * NPT * 3;

    int len = 0;
    for (int c0 = 0; c0 < NPT; c0 += 256) {
        const int idx = c0 + tid;
        const float x = bxyz[idx * 3 + 0];
        const float y = bxyz[idx * 3 + 1];
        const float z = bxyz[idx * 3 + 2];
        const float nb = __fadd_rn(
            __fadd_rn(__fmul_rn(x, x), __fmul_rn(y, y)), __fmul_rn(z, z));
        // dot as FMA chain (dot_general / matmul emitter semantics)
        const float dt = __fmaf_rn(sz, z, __fmaf_rn(sy, y, __fmul_rn(sx, x)));
        const float d2 = __fsub_rn(__fadd_rn(na, nb), __fmul_rn(2.0f, dt));
        const bool within = d2 < 0.04f;   // f32(0.2*0.2)

        const unsigned long long m = __ballot(within);
        const int wvq  = tid >> 6;
        const int lane = tid & 63;
        if (lane == 0) wavecnt[wvq] = __popcll(m);
        __syncthreads();
        const int w0 = wavecnt[0], w1 = wavecnt[1], w2 = wavecnt[2], w3 = wavecnt[3];
        int off = len;
        if (wvq > 0) off += w0;
        if (wvq > 1) off += w1;
        if (wvq > 2) off += w2;
        const int pre = __popcll(m & ((1ull << lane) - 1ull));
        const int pos = off + pre;
        if (within && pos < NK) list[pos] = idx;
        len += w0 + w1 + w2 + w3;
        __syncthreads();   // also orders list[] writes before gather reads
        if (len >= NK) break;
    }
    const int llen = len < NK ? len : NK;

    // gather: one wave per neighbor row (256 floats = 64 lanes x float4)
    const int lane = tid & 63;
    const int sub  = tid >> 6;   // 4 rows in flight per pass
    const float4* fbase = (const float4*)(feat + (size_t)b * NPT * NC);
    float4* obase = (float4*)(out_feat + (((size_t)b * NS + s) * (size_t)NK) * NC);
#pragma unroll
    for (int p = 0; p < NK / 4; ++p) {
        const int k   = p * 4 + sub;
        const int row = (k < llen) ? list[k] : NS;   // pad -> feat row 1024
        const float4 v = fbase[(size_t)row * (NC / 4) + lane];
        obase[(size_t)k * (NC / 4) + lane] = v;
    }
}

extern "C" void kernel_launch(void* const* d_in, const int* in_sizes, int n_in,
                              void* d_out, int out_size, void* d_ws, size_t ws_size,
                              hipStream_t stream) {
    const float* xyz  = (const float*)d_in[0];
    const float* feat = (const float*)d_in[1];
    float* out        = (float*)d_out;
    float* sample_xyz = out;                          // (B,S,3) = 12288 floats
    float* out_feat   = out + (size_t)NB * NS * 3;    // (B,S,K,C)

    fps_kernel<<<dim3(NB), dim3(512), 0, stream>>>(xyz, sample_xyz);
    bq_gather_kernel<<<dim3(NS, NB), dim3(256), 0, stream>>>(
        xyz, feat, sample_xyz, out_feat);
}

// Round 7
// 876.383 us; speedup vs baseline: 1.2212x; 1.2212x over previous
//
#include <hip/hip_runtime.h>
#include <cstdint>

#define NB   4      // batches
#define NPT  8192   // points
#define NC   256    // feature channels
#define NS   1024   // FPS samples
#define NK   64     // neighbors per ball
#define FPT  32     // points per thread in FPS (8192 / 256 threads)

typedef float v2f __attribute__((ext_vector_type(2)));

// ---------------------------------------------------------------------------
// DPP max step (f32, old=0 fill — safe: all reduced values >= 0).
// ---------------------------------------------------------------------------
template <int CTRL, int RMASK>
__device__ __forceinline__ float dpp_max_step(float x) {
    const int t = __builtin_amdgcn_update_dpp(
        0, __float_as_int(x), CTRL, RMASK, 0xf, false);
    return fmaxf(x, __int_as_float(t));
}
__device__ __forceinline__ float wave_max_f32(float x) {
    x = dpp_max_step<0x111, 0xf>(x);  // row_shr:1
    x = dpp_max_step<0x112, 0xf>(x);  // row_shr:2
    x = dpp_max_step<0x114, 0xf>(x);  // row_shr:4
    x = dpp_max_step<0x118, 0xf>(x);  // row_shr:8
    x = dpp_max_step<0x142, 0xa>(x);  // row_bcast:15 -> rows 1,3
    x = dpp_max_step<0x143, 0xc>(x);  // row_bcast:31 -> rows 2,3
    return x;                          // lane 63 holds wave max
}

// ---------------------------------------------------------------------------
// Kernel 1: farthest point sampling. One 256-thread block (4 waves = 1 per
// SIMD) per batch. Same per-SIMD issue work as the 8-wave version, but half
// the barrier participants (less skew at each of 1024 barriers), half the
// atomicMax contention, and no competing-wave issue interleaving.
// Handshake = round-5 structure (empirically best; round-6's DPP-select
// regressed +500 cyc/step — cross-lane op chains serialize worse than
// modeled):
//  - cross-wave winner via LDS atomicMax(u64) into a 3-slot rotating buffer;
//    post-barrier is a single broadcast ds_read_b64.
//    3-slot zeroing proof: slot[nxt] (= slot used at step s+1) was last READ
//    at step s-2's post-barrier phase, which happens-before barrier(s-1),
//    which happens-before tid0's zeroing at step s pre-barrier; the zero is
//    ordered before step s+1's atomics by barrier(s). No race.
//  - sample_xyz accumulated in LDS, flushed coalesced at the end.
// First-occurrence argmax: lane's 32 points split x-half = tid*32+0..15,
// y-half = tid*32+16..31; strict-> per half keeps the earliest index; halves
// combined preferring x (all x indices < all y indices). Lanes/waves own
// ascending contiguous blocks, so lowest achieving lane (ballot+ffs) = first
// occurrence; cross-wave via packed key (valbits<<32)|(0xFFFFFFFF-idx).
// NOTE: non-FMA left-to-right distance arithmetic (contract off) is VERIFIED
// bit-exact vs the reference (rounds 1-6). Do not "optimize" into FMA.
// ---------------------------------------------------------------------------
__global__ __launch_bounds__(256, 1) void fps_kernel(
    const float* __restrict__ xyz, float* __restrict__ sample_xyz)
{
    const int b   = blockIdx.x;
    const int tid = threadIdx.x;

    __shared__ float Xs[NPT], Ys[NPT], Zs[NPT];        // 96 KB SoA copy
    __shared__ float Samp[NS * 3];                     // 12 KB result buffer
    __shared__ unsigned long long slots[3];            // rotating winner slots

    const float* base = xyz + (size_t)b * NPT * 3;

    v2f px[16], py[16], pz[16], md[16];
#pragma unroll
    for (int j = 0; j < 16; ++j) {
        const int pa = tid * FPT + j;         // x-half point
        const int pb = tid * FPT + 16 + j;    // y-half point
        const float ax = base[pa * 3 + 0], ay = base[pa * 3 + 1], az = base[pa * 3 + 2];
        const float bx = base[pb * 3 + 0], by = base[pb * 3 + 1], bz = base[pb * 3 + 2];
        px[j] = (v2f){ax, bx};
        py[j] = (v2f){ay, by};
        pz[j] = (v2f){az, bz};
        md[j] = (v2f){__builtin_inff(), __builtin_inff()};
        Xs[pa] = ax; Ys[pa] = ay; Zs[pa] = az;
        Xs[pb] = bx; Ys[pb] = by; Zs[pb] = bz;
    }
    if (tid < 3) slots[tid] = 0ull;
    __syncthreads();

    int widx = 0;           // deterministic start at index 0 (matches reference)
    int cur = 0, nxt = 1;   // rotating slot indices (avoid % in the loop)
    for (int s = 0; s < NS; ++s) {
        // centroid xyz: uniform-address LDS broadcast reads
        const float sx = Xs[widx];
        const float sy = Ys[widx];
        const float sz = Zs[widx];
        if (tid == 0) {
            Samp[s * 3 + 0] = sx; Samp[s * 3 + 1] = sy; Samp[s * 3 + 2] = sz;
            slots[nxt] = 0ull;   // safe per 3-slot proof above
        }

        const v2f sxv = (v2f){sx, sx};
        const v2f syv = (v2f){sy, sy};
        const v2f szv = (v2f){sz, sz};

        v2f best2 = (v2f){-1.0f, -1.0f};
        int jx = 0, jy = 0;
        {
#pragma clang fp contract(off)
#pragma unroll
            for (int j = 0; j < 16; ++j) {
                // EXACT reference arithmetic per element:
                // ((dx*dx + dy*dy) + dz*dz), no FMA (contract off)
                const v2f dx = px[j] - sxv;
                const v2f dy = py[j] - syv;
                const v2f dz = pz[j] - szv;
                const v2f d  = (dx * dx + dy * dy) + dz * dz;
                const v2f m  = __builtin_elementwise_min(md[j], d);
                md[j] = m;
                // strict > keeps first occurrence within each half
                if (m.x > best2.x) jx = j;
                if (m.y > best2.y) jy = j;
                best2 = __builtin_elementwise_max(best2, m);
            }
        }
        // combine halves: every x-half index < every y-half index
        float    bestval;
        unsigned bestidx;
        if (best2.y > best2.x) { bestval = best2.y; bestidx = (unsigned)(tid * FPT + 16 + jy); }
        else                   { bestval = best2.x; bestidx = (unsigned)(tid * FPT + jx); }

        // wave max via DPP (VALU pipe), then first achieving lane via ballot
        const float wmax = wave_max_f32(bestval);
        const float smax = __int_as_float(
            __builtin_amdgcn_readlane(__float_as_int(wmax), 63));
        const unsigned long long msk = __ballot(bestval == smax);
        const int wl = __ffsll((long long)msk) - 1;          // lowest lane
        const unsigned widx_w =
            (unsigned)__builtin_amdgcn_readlane((int)bestidx, wl);
        if ((tid & 63) == 0) {
            const unsigned long long key =
                ((unsigned long long)__float_as_uint(smax) << 32)
                | (unsigned long long)(0xFFFFFFFFu - widx_w);
            atomicMax(&slots[cur], key);     // ds_max_u64, fire-and-forget
        }
        __syncthreads();

        // broadcast read of the winning key
        const unsigned long long best = slots[cur];
        widx = (int)(0xFFFFFFFFu - (unsigned)(best & 0xFFFFFFFFull));
        cur = nxt;
        nxt = (nxt == 2) ? 0 : nxt + 1;
    }

    // coalesced flush of the sample buffer
    float* o = sample_xyz + (size_t)b * NS * 3;
    for (int i = tid; i < NS * 3; i += 256) o[i] = Samp[i];
}

// ---------------------------------------------------------------------------
// Kernel 2: ball query (first-64 in-radius indices, ascending) + feature
// gather. One 256-thread block per (b, s) centroid. Early-exit scan.
// d2 = na + nb - 2*dot; dot is an FMA CHAIN (XLA dot_general semantics),
// na/nb are non-FMA square-sums (XLA reduce semantics). VERIFIED rounds 2-6.
// ---------------------------------------------------------------------------
__global__ __launch_bounds__(256) void bq_gather_kernel(
    const float* __restrict__ xyz, const float* __restrict__ feat,
    const float* __restrict__ sample_xyz, float* __restrict__ out_feat)
{
    const int s   = blockIdx.x;
    const int b   = blockIdx.y;
    const int tid = threadIdx.x;

    __shared__ int   list[NK];
    __shared__ int   wavecnt[4];
    __shared__ float cen[3];

    if (tid < 3) cen[tid] = sample_xyz[((size_t)b * NS + s) * 3 + tid];
    __syncthreads();
    const float sx = cen[0], sy = cen[1], sz = cen[2];
    const float na = __fadd_rn(
        __fadd_rn(__fmul_rn(sx, sx), __fmul_rn(sy, sy)), __fmul_rn(sz, sz));
    const float* bxyz = xyz + (size_t)b * NPT * 3;

    int len = 0;
    for (int c0 = 0; c0 < NPT; c0 += 256) {
        const int idx = c0 + tid;
        const float x = bxyz[idx * 3 + 0];
        const float y = bxyz[idx * 3 + 1];
        const float z = bxyz[idx * 3 + 2];
        const float nb = __fadd_rn(
            __fadd_rn(__fmul_rn(x, x), __fmul_rn(y, y)), __fmul_rn(z, z));
        // dot as FMA chain (dot_general / matmul emitter semantics)
        const float dt = __fmaf_rn(sz, z, __fmaf_rn(sy, y, __fmul_rn(sx, x)));
        const float d2 = __fsub_rn(__fadd_rn(na, nb), __fmul_rn(2.0f, dt));
        const bool within = d2 < 0.04f;   // f32(0.2*0.2)

        const unsigned long long m = __ballot(within);
        const int wvq  = tid >> 6;
        const int lane = tid & 63;
        if (lane == 0) wavecnt[wvq] = __popcll(m);
        __syncthreads();
        const int w0 = wavecnt[0], w1 = wavecnt[1], w2 = wavecnt[2], w3 = wavecnt[3];
        int off = len;
        if (wvq > 0) off += w0;
        if (wvq > 1) off += w1;
        if (wvq > 2) off += w2;
        const int pre = __popcll(m & ((1ull << lane) - 1ull));
        const int pos = off + pre;
        if (within && pos < NK) list[pos] = idx;
        len += w0 + w1 + w2 + w3;
        __syncthreads();   // also orders list[] writes before gather reads
        if (len >= NK) break;
    }
    const int llen = len < NK ? len : NK;

    // gather: one wave per neighbor row (256 floats = 64 lanes x float4)
    const int lane = tid & 63;
    const int sub  = tid >> 6;   // 4 rows in flight per pass
    const float4* fbase = (const float4*)(feat + (size_t)b * NPT * NC);
    float4* obase = (float4*)(out_feat + (((size_t)b * NS + s) * (size_t)NK) * NC);
#pragma unroll
    for (int p = 0; p < NK / 4; ++p) {
        const int k   = p * 4 + sub;
        const int row = (k < llen) ? list[k] : NS;   // pad -> feat row 1024
        const float4 v = fbase[(size_t)row * (NC / 4) + lane];
        obase[(size_t)k * (NC / 4) + lane] = v;
    }
}

extern "C" void kernel_launch(void* const* d_in, const int* in_sizes, int n_in,
                              void* d_out, int out_size, void* d_ws, size_t ws_size,
                              hipStream_t stream) {
    const float* xyz  = (const float*)d_in[0];
    const float* feat = (const float*)d_in[1];
    float* out        = (float*)d_out;
    float* sample_xyz = out;                          // (B,S,3) = 12288 floats
    float* out_feat   = out + (size_t)NB * NS * 3;    // (B,S,K,C)

    fps_kernel<<<dim3(NB), dim3(256), 0, stream>>>(xyz, sample_xyz);
    bq_gather_kernel<<<dim3(NS, NB), dim3(256), 0, stream>>>(
        xyz, feat, sample_xyz, out_feat);
}